// Round 3
// baseline (457.489 us; speedup 1.0000x reference)
//
#include <hip/hip_runtime.h>

// EUNN: 256 layers; each layer = rotation on even pairs (2i,2i+1), then
// rotation on odd pairs (2i+1,2i+2 mod H).
// Pair math: y0 = e^{i*phi} (ct*u - st*v); y1 = st*u + ct*v.

#define H_DIM 1024
#define C2 256
#define RPW 4   // batch rows per wave

// coef layout: [c][phase][j][lane] as float4 (ct, st, cp, sp), pair i = 8*lane + j
// -> flat float4 index: ((c*2 + phase)*8 + j)*64 + lane,  4 MB total.

__global__ __launch_bounds__(256) void eunn_coef_kernel(
    const float* __restrict__ phi0, const float* __restrict__ theta0,
    const float* __restrict__ phi1, const float* __restrict__ theta1,
    float4* __restrict__ coef) {
    int t = blockIdx.x * 256 + threadIdx.x;     // [0, 256*2*512)
    int i = t & 511;                            // pair index
    int p = (t >> 9) & 1;                       // phase (0: even pairs, 1: odd pairs)
    int c = t >> 10;                            // layer
    const float* phi   = p ? phi1   : phi0;
    const float* theta = p ? theta1 : theta0;
    float ph = phi[i * C2 + c];
    float th = theta[i * C2 + c];
    float sp, cp, st, ct;
    __sincosf(ph, &sp, &cp);
    __sincosf(th, &st, &ct);
    int j = i & 7;
    int l = i >> 3;
    coef[(((c * 2 + p) * 8) + j) * 64 + l] = make_float4(ct, st, cp, sp);
}

__device__ __forceinline__ void rot_pair(const float4 q,
                                         float& ur, float& ui,
                                         float& wr, float& wi) {
    // q = (ct, st, cp, sp)
    float ar = fmaf(-q.y, wr, q.x * ur);   // ct*u - st*v (real part)
    float ai = fmaf(-q.y, wi, q.x * ui);
    float br = fmaf( q.x, wr, q.y * ur);   // st*u + ct*v
    float bi = fmaf( q.x, wi, q.y * ui);
    ur = fmaf(-q.w, ai, q.z * ar);         // e^{i phi} * a
    ui = fmaf( q.w, ar, q.z * ai);
    wr = br;
    wi = bi;
}

// Session ledger:
//  R1: 4x float4[8] reg prefetch at RPW=2 -> ~200 VGPR demand vs 128 cap ->
//      scratch spill (WRITE_SIZE 33MB->1.66GB), 902us. Bounded prefetch only.
//  R2: block-wide LDS staging at RPW=2 -> LDS pipe oversubscribed (136
//      ds_read_b128/layer/CU ~1630cy > 1536cy VALU) + 2 barrier drains/layer,
//      424us, VALUBusy 54%. LDS staging is a dead end at RPW=2.
//  Structural fact: at RPW=2 coef traffic = 8.6GB from L2; at the 164us VALU
//      floor that is 52 TB/s > 34.5 TB/s L2 ceiling. Must amortize coefs over
//      more rows.
//  R3 (this): RPW=4, direct L2 coef loads, no LDS, no barriers. Coef traffic
//      4.3GB (~22TB/s at 200us, 62% of L2 ceiling). 1 wave/SIMD; latency hidden
//      by bounded reg pipeline: B[8] issued at layer top (used after phase A),
//      next A[8] issued mid-layer (used next iter). 64 coef VGPRs, ~225 total,
//      under the 512 cap at (256,1).
__global__ __launch_bounds__(256, 1) void eunn_main_kernel(
    const float* __restrict__ x,
    const float4* __restrict__ coef,
    float* __restrict__ out) {
    const int lane = threadIdx.x & 63;
    const int wave = threadIdx.x >> 6;
    const int row0 = (blockIdx.x * 4 + wave) * RPW;
    const int lnext = (lane + 1) & 63;
    const int lprev = (lane + 63) & 63;

    // lane owns complex elements [16*lane, 16*lane+16) of each of its RPW rows
    float vr[RPW][16], vi[RPW][16];

#pragma unroll
    for (int r = 0; r < RPW; ++r) {
        const float4* src = (const float4*)(x + (size_t)(row0 + r) * (H_DIM * 2)) + lane * 8;
#pragma unroll
        for (int m = 0; m < 8; ++m) {
            float4 f = src[m];
            vr[r][2 * m]     = f.x; vi[r][2 * m]     = f.y;
            vr[r][2 * m + 1] = f.z; vi[r][2 * m + 1] = f.w;
        }
    }

    const float4* cl = coef + lane;   // lane-offset base

    // A holds the CURRENT layer's phase-A coefs (prefetched during the
    // previous layer's phase B). B is loaded at layer top, consumed after
    // phase A. Bounded: 16 float4 = 64 VGPRs of coef state.
    float4 A[8], B[8];
#pragma unroll
    for (int j = 0; j < 8; ++j) A[j] = cl[j * 64];   // layer 0, phase A

#pragma unroll 1
    for (int c = 0; c < C2; ++c) {
        const float4* cb = cl + (size_t)c * 1024;

        // Issue phase-B loads now; first use is ~1500cy away (after phase A).
#pragma unroll
        for (int j = 0; j < 8; ++j) B[j] = cb[(8 + j) * 64];
        // Pin the load batch above phase-A compute (don't let the scheduler
        // sink loads toward their uses to save registers — R0 failure mode).
        __builtin_amdgcn_sched_barrier(0);

        // --- phase A: pairs (2j, 2j+1), all j
#pragma unroll
        for (int j = 0; j < 8; ++j) {
#pragma unroll
            for (int r = 0; r < RPW; ++r)
                rot_pair(A[j], vr[r][2 * j],     vi[r][2 * j],
                               vr[r][2 * j + 1], vi[r][2 * j + 1]);
        }

        // B has arrived (phase A covered its latency). Boundary coef + the
        // cross-lane state shuffles on post-phase-A values; results are used
        // at the END of phase B (~600cy of slack over the DS latency).
        float4 qq = B[7];
        float qpx = __shfl(qq.x, lprev);   // prev lane's ct'
        float qpy = __shfl(qq.y, lprev);   // prev lane's st'
        float nbr[RPW], nbi[RPW], pbr[RPW], pbi[RPW];
#pragma unroll
        for (int r = 0; r < RPW; ++r) {
            nbr[r] = __shfl(vr[r][0],  lnext);   // next lane's elem0
            nbi[r] = __shfl(vi[r][0],  lnext);
            pbr[r] = __shfl(vr[r][15], lprev);   // prev lane's elem15
            pbi[r] = __shfl(vi[r][15], lprev);
        }

        // Prefetch next layer's phase-A coefs (A is dead after phase A).
        const int cn = (c + 1 < C2) ? (c + 1) : 0;   // last iter: dummy
        const float4* cnp = cl + (size_t)cn * 1024;
#pragma unroll
        for (int j = 0; j < 8; ++j) A[j] = cnp[j * 64];
        __builtin_amdgcn_sched_barrier(0);

        // --- phase B internal pairs (local 2j+1, 2j+2), j=0..6
#pragma unroll
        for (int j = 0; j < 7; ++j) {
#pragma unroll
            for (int r = 0; r < RPW; ++r)
                rot_pair(B[j], vr[r][2 * j + 1], vi[r][2 * j + 1],
                               vr[r][2 * j + 2], vi[r][2 * j + 2]);
        }

        // --- phase B boundary pair (my elem15, next lane's elem0)
#pragma unroll
        for (int r = 0; r < RPW; ++r) {
            // new elem15 = e^{i phi}(ct*e15 - st*next_e0)
            float ar = fmaf(-qq.y, nbr[r], qq.x * vr[r][15]);
            float ai = fmaf(-qq.y, nbi[r], qq.x * vi[r][15]);
            vr[r][15] = fmaf(-qq.w, ai, qq.z * ar);
            vi[r][15] = fmaf( qq.w, ar, qq.z * ai);
            // new elem0 = st'*prev_e15 + ct'*e0
            float b0r = fmaf(qpx, vr[r][0], qpy * pbr[r]);
            float b0i = fmaf(qpx, vi[r][0], qpy * pbi[r]);
            vr[r][0] = b0r; vi[r][0] = b0i;
        }
    }

#pragma unroll
    for (int r = 0; r < RPW; ++r) {
        float4* dst = (float4*)(out + (size_t)(row0 + r) * (H_DIM * 2)) + lane * 8;
#pragma unroll
        for (int m = 0; m < 8; ++m) {
            dst[m] = make_float4(vr[r][2 * m],     vi[r][2 * m],
                                 vr[r][2 * m + 1], vi[r][2 * m + 1]);
        }
    }
}

extern "C" void kernel_launch(void* const* d_in, const int* in_sizes, int n_in,
                              void* d_out, int out_size, void* d_ws, size_t ws_size,
                              hipStream_t stream) {
    const float* x      = (const float*)d_in[0];
    const float* phi0   = (const float*)d_in[1];
    const float* theta0 = (const float*)d_in[2];
    const float* phi1   = (const float*)d_in[3];
    const float* theta1 = (const float*)d_in[4];
    float* out = (float*)d_out;
    float4* coef = (float4*)d_ws;   // 256*1024 float4 = 4 MB

    // coefficients: 256 layers * 2 phases * 512 pairs = 262144 threads
    hipLaunchKernelGGL(eunn_coef_kernel, dim3(1024), dim3(256), 0, stream,
                       phi0, theta0, phi1, theta1, coef);

    // main: 4096 rows / (4 waves/block * RPW rows/wave) = 256 blocks
    hipLaunchKernelGGL(eunn_main_kernel, dim3(256), dim3(256), 0, stream,
                       x, coef, out);
}